// Round 4
// baseline (508.933 us; speedup 1.0000x reference)
//
#include <hip/hip_runtime.h>

// BP-MLL loss: B=8192 rows, L=10000 cols, fp32 x + i32 target.
// Factorized: per-row (sum_{pos} exp(-x)) * (sum_{neg} exp(x)) / (n_pos*n_neg),
// summed over rows. Memory-bound: 655 MB compulsory reads @ ~6.4 TB/s achieved.
// R4: fuse final reduction into the row kernel via fence+counter last-block
// pattern (saves one launch + ~3-5 us). Deterministic: last block sums rows
// in fixed order; agent-scope atomics handle cross-XCD visibility.

constexpr int B = 8192;
constexpr int L = 10000;
constexpr int L4 = L / 4;  // 2500 x 16B per row

typedef float fx4 __attribute__((ext_vector_type(4)));
typedef int ix4 __attribute__((ext_vector_type(4)));

__device__ inline fx4 ntload4f(const fx4* p) { return __builtin_nontemporal_load(p); }
__device__ inline ix4 ntload4i(const ix4* p) { return __builtin_nontemporal_load(p); }

__global__ __launch_bounds__(256) void bpmll_fused(const float* __restrict__ x,
                                                   const int* __restrict__ tgt,
                                                   float* __restrict__ out,
                                                   float* __restrict__ row_buf,
                                                   int* __restrict__ counter) {
    const int row = blockIdx.x;
    const fx4* __restrict__ xr = reinterpret_cast<const fx4*>(x + (size_t)row * L);
    const ix4* __restrict__ tr = reinterpret_cast<const ix4*>(tgt + (size_t)row * L);

    float s_pos = 0.f, s_neg = 0.f;
    int n_pos = 0;

#define PROC(vv, tt)                                   \
    do {                                               \
        bool p = (tt != 0);                            \
        float e = __expf(p ? -vv : vv);                \
        s_pos += p ? e : 0.f;                          \
        s_neg += p ? 0.f : e;                          \
        n_pos += tt;                                   \
    } while (0)

    // tid in [0,256) < L4=2500, so the prologue load is unconditionally valid.
    int i = threadIdx.x;
    fx4 v = ntload4f(&xr[i]);
    ix4 t = ntload4i(&tr[i]);

    for (int j = i + 256; j < L4; j += 256) {
        // prefetch next iteration before consuming current
        fx4 vn = ntload4f(&xr[j]);
        ix4 tn = ntload4i(&tr[j]);
        PROC(v.x, t.x);
        PROC(v.y, t.y);
        PROC(v.z, t.z);
        PROC(v.w, t.w);
        v = vn;
        t = tn;
    }
    PROC(v.x, t.x);
    PROC(v.y, t.y);
    PROC(v.z, t.z);
    PROC(v.w, t.w);
#undef PROC

    // wave (64-lane) reduction
    #pragma unroll
    for (int off = 32; off > 0; off >>= 1) {
        s_pos += __shfl_down(s_pos, off);
        s_neg += __shfl_down(s_neg, off);
        n_pos += __shfl_down(n_pos, off);
    }

    __shared__ float sp[4], sn[4];
    __shared__ int np[4];
    __shared__ bool is_last;
    const int wave = threadIdx.x >> 6;
    const int lane = threadIdx.x & 63;
    if (lane == 0) { sp[wave] = s_pos; sn[wave] = s_neg; np[wave] = n_pos; }
    __syncthreads();

    if (threadIdx.x == 0) {
        float P = sp[0] + sp[1] + sp[2] + sp[3];
        float N = sn[0] + sn[1] + sn[2] + sn[3];
        int npos = np[0] + np[1] + np[2] + np[3];
        float k = (float)npos * (float)(L - npos);
        float r = P * N / k;
        // agent-scope store + release fetch_add: row result visible to the
        // block that observes the final counter value (cross-XCD safe).
        __hip_atomic_store(&row_buf[row], r, __ATOMIC_RELAXED, __HIP_MEMORY_SCOPE_AGENT);
        int prev = __hip_atomic_fetch_add(counter, 1, __ATOMIC_ACQ_REL, __HIP_MEMORY_SCOPE_AGENT);
        is_last = (prev == (int)gridDim.x - 1);
    }
    __syncthreads();

    if (is_last) {
        // Final reduction over B=8192 row values, fixed order -> deterministic.
        float s = 0.f;
        for (int idx = threadIdx.x; idx < B; idx += 256)
            s += __hip_atomic_load(&row_buf[idx], __ATOMIC_RELAXED, __HIP_MEMORY_SCOPE_AGENT);

        #pragma unroll
        for (int off = 32; off > 0; off >>= 1) s += __shfl_down(s, off);

        if (lane == 0) sp[wave] = s;
        __syncthreads();
        if (threadIdx.x == 0) out[0] = sp[0] + sp[1] + sp[2] + sp[3];
    }
}

extern "C" void kernel_launch(void* const* d_in, const int* in_sizes, int n_in,
                              void* d_out, int out_size, void* d_ws, size_t ws_size,
                              hipStream_t stream) {
    const float* x = (const float*)d_in[0];
    const int* tgt = (const int*)d_in[1];
    float* out = (float*)d_out;
    float* row_buf = (float*)d_ws;              // 8192 floats = 32 KB
    int* counter = (int*)((char*)d_ws + B * sizeof(float));

    hipMemsetAsync(counter, 0, sizeof(int), stream);
    bpmll_fused<<<B, 256, 0, stream>>>(x, tgt, out, row_buf, counter);
}

// Round 5
// 106.353 us; speedup vs baseline: 4.7853x; 4.7853x over previous
//
#include <hip/hip_runtime.h>

// BP-MLL loss: B=8192 rows, L=10000 cols, fp32 x + i32 target.
// Factorized: per-row (sum_{pos} exp(-x)) * (sum_{neg} exp(x)) / (n_pos*n_neg),
// summed over rows. Memory-bound: 655 MB compulsory reads @ ~6.4 TB/s achieved.
// R5: revert to the R3 two-kernel structure. R4's fused last-block pattern
// (per-block agent-scope acq_rel atomics) collapsed BW 6.4 TB/s -> 0.67 TB/s:
// each block's fence invalidates L1/L2 under every other streaming block.
// Two plain launches cost ~4 us total and leave the stream path clean.

constexpr int B = 8192;
constexpr int L = 10000;
constexpr int L4 = L / 4;  // 2500 x 16B per row

typedef float fx4 __attribute__((ext_vector_type(4)));
typedef int ix4 __attribute__((ext_vector_type(4)));

__device__ inline fx4 ntload4f(const fx4* p) { return __builtin_nontemporal_load(p); }
__device__ inline ix4 ntload4i(const ix4* p) { return __builtin_nontemporal_load(p); }

__global__ __launch_bounds__(256) void bpmll_rows(const float* __restrict__ x,
                                                  const int* __restrict__ tgt,
                                                  float* __restrict__ row_out) {
    const int row = blockIdx.x;
    const fx4* __restrict__ xr = reinterpret_cast<const fx4*>(x + (size_t)row * L);
    const ix4* __restrict__ tr = reinterpret_cast<const ix4*>(tgt + (size_t)row * L);

    float s_pos = 0.f, s_neg = 0.f;
    int n_pos = 0;

#define PROC(vv, tt)                                   \
    do {                                               \
        bool p = (tt != 0);                            \
        float e = __expf(p ? -vv : vv);                \
        s_pos += p ? e : 0.f;                          \
        s_neg += p ? 0.f : e;                          \
        n_pos += tt;                                   \
    } while (0)

    // tid in [0,256) < L4=2500, so the prologue load is unconditionally valid.
    int i = threadIdx.x;
    fx4 v = ntload4f(&xr[i]);
    ix4 t = ntload4i(&tr[i]);

    for (int j = i + 256; j < L4; j += 256) {
        // prefetch next iteration before consuming current
        fx4 vn = ntload4f(&xr[j]);
        ix4 tn = ntload4i(&tr[j]);
        PROC(v.x, t.x);
        PROC(v.y, t.y);
        PROC(v.z, t.z);
        PROC(v.w, t.w);
        v = vn;
        t = tn;
    }
    PROC(v.x, t.x);
    PROC(v.y, t.y);
    PROC(v.z, t.z);
    PROC(v.w, t.w);
#undef PROC

    // wave (64-lane) reduction
    #pragma unroll
    for (int off = 32; off > 0; off >>= 1) {
        s_pos += __shfl_down(s_pos, off);
        s_neg += __shfl_down(s_neg, off);
        n_pos += __shfl_down(n_pos, off);
    }

    __shared__ float sp[4], sn[4];
    __shared__ int np[4];
    const int wave = threadIdx.x >> 6;
    const int lane = threadIdx.x & 63;
    if (lane == 0) { sp[wave] = s_pos; sn[wave] = s_neg; np[wave] = n_pos; }
    __syncthreads();

    if (threadIdx.x == 0) {
        float P = sp[0] + sp[1] + sp[2] + sp[3];
        float N = sn[0] + sn[1] + sn[2] + sn[3];
        int npos = np[0] + np[1] + np[2] + np[3];
        float k = (float)npos * (float)(L - npos);
        row_out[row] = P * N / k;
    }
}

__global__ __launch_bounds__(1024) void bpmll_final(const float* __restrict__ rows,
                                                    float* __restrict__ out) {
    float s = 0.f;
    for (int i = threadIdx.x; i < B; i += 1024) s += rows[i];

    #pragma unroll
    for (int off = 32; off > 0; off >>= 1) s += __shfl_down(s, off);

    __shared__ float w[16];
    const int wave = threadIdx.x >> 6;
    const int lane = threadIdx.x & 63;
    if (lane == 0) w[wave] = s;
    __syncthreads();

    if (threadIdx.x == 0) {
        float t = 0.f;
        #pragma unroll
        for (int i = 0; i < 16; i++) t += w[i];
        out[0] = t;
    }
}

extern "C" void kernel_launch(void* const* d_in, const int* in_sizes, int n_in,
                              void* d_out, int out_size, void* d_ws, size_t ws_size,
                              hipStream_t stream) {
    const float* x = (const float*)d_in[0];
    const int* tgt = (const int*)d_in[1];
    float* out = (float*)d_out;
    float* row_out = (float*)d_ws;  // 8192 floats = 32 KB scratch

    bpmll_rows<<<B, 256, 0, stream>>>(x, tgt, row_out);
    bpmll_final<<<1, 1024, 0, stream>>>(row_out, out);
}